// Round 1
// baseline (1712.034 us; speedup 1.0000x reference)
//
#include <hip/hip_runtime.h>
#include <hip/hip_bf16.h>
#include <cstdint>

#define NUM_GRAPHS 128
constexpr float EPSF = 1e-5f;

// ---------------- count incoming edges per node ----------------
__global__ __launch_bounds__(256) void count_kernel(const int* __restrict__ dst,
                                                    float* __restrict__ cnt, int E) {
  int e = blockIdx.x * 256 + threadIdx.x;
  if (e < E) atomicAdd(&cnt[dst[e]], 1.0f);
}

// ---------------- edge scatter: agg[dst] += h[src]  (D = pow2) ----------------
template <int D>
__global__ __launch_bounds__(256) void scatter_kernel(const float* __restrict__ h,
                                                      const int* __restrict__ src,
                                                      const int* __restrict__ dst,
                                                      float* __restrict__ agg, int E) {
  int idx = blockIdx.x * 256 + threadIdx.x;
  if (idx >= E * D) return;
  int e = idx / D;
  int f = idx & (D - 1);
  atomicAdd(&agg[(size_t)dst[e] * D + f], h[(size_t)src[e] * D + f]);
}

// ---------------- weight vector load ----------------
template <int RJ>
__device__ __forceinline__ void loadw(const float* __restrict__ p, float* w) {
  if constexpr (RJ == 1) {
    w[0] = p[0];
  } else if constexpr (RJ == 4) {
    const float4 v = *reinterpret_cast<const float4*>(p);
    w[0] = v.x; w[1] = v.y; w[2] = v.z; w[3] = v.w;
  } else {
    const float4 v0 = *reinterpret_cast<const float4*>(p);
    const float4 v1 = *reinterpret_cast<const float4*>(p + 4);
    w[0] = v0.x; w[1] = v0.y; w[2] = v0.z; w[3] = v0.w;
    w[4] = v1.x; w[5] = v1.y; w[6] = v1.z; w[7] = v1.w;
  }
}

// ---------------- node linear: out = (agg/max(cnt,1)) @ wl + b + x @ wr ----------------
// block = 256 threads = 16(ty, node) x 16(tx, j). Tile: 64 nodes x (16*RJ) outputs.
template <int DIN, int DOUT, int RJ>
__global__ __launch_bounds__(256) void linear_kernel(
    const float* __restrict__ agg, const float* __restrict__ cnt,
    const float* __restrict__ xin, const float* __restrict__ wl,
    const float* __restrict__ bias, const float* __restrict__ wr,
    float* __restrict__ out, int N) {
  constexpr int K2P = 2 * DIN + 1;  // mean | x rows, +1 pad
  __shared__ float As[64 * K2P];
  const int nb = blockIdx.x * 64;
  const int tid = threadIdx.x;

  for (int idx = tid; idx < 64 * DIN; idx += 256) {
    int nl = idx / DIN, k = idx % DIN;
    int n = nb + nl;
    float mv = 0.f, xv = 0.f;
    if (n < N) {
      float c = fmaxf(cnt[n], 1.0f);
      mv = agg[(size_t)n * DIN + k] / c;
      xv = xin[(size_t)n * DIN + k];
    }
    As[nl * K2P + k] = mv;
    As[nl * K2P + DIN + k] = xv;
  }
  __syncthreads();

  const int ty = tid >> 4, tx = tid & 15;
  const int j0 = blockIdx.y * (16 * RJ) + tx * RJ;
  float acc[4][RJ];
#pragma unroll
  for (int r = 0; r < 4; ++r)
#pragma unroll
    for (int c = 0; c < RJ; ++c) acc[r][c] = 0.f;

  const float* A0 = &As[(ty * 4 + 0) * K2P];
  const float* A1 = &As[(ty * 4 + 1) * K2P];
  const float* A2 = &As[(ty * 4 + 2) * K2P];
  const float* A3 = &As[(ty * 4 + 3) * K2P];

#pragma unroll 4
  for (int k = 0; k < DIN; ++k) {  // mean part
    float w[RJ];
    loadw<RJ>(wl + (size_t)k * DOUT + j0, w);
    float a0 = A0[k], a1 = A1[k], a2 = A2[k], a3 = A3[k];
#pragma unroll
    for (int c = 0; c < RJ; ++c) {
      acc[0][c] = fmaf(a0, w[c], acc[0][c]);
      acc[1][c] = fmaf(a1, w[c], acc[1][c]);
      acc[2][c] = fmaf(a2, w[c], acc[2][c]);
      acc[3][c] = fmaf(a3, w[c], acc[3][c]);
    }
  }
#pragma unroll 4
  for (int k = 0; k < DIN; ++k) {  // root part
    float w[RJ];
    loadw<RJ>(wr + (size_t)k * DOUT + j0, w);
    float a0 = A0[DIN + k], a1 = A1[DIN + k], a2 = A2[DIN + k], a3 = A3[DIN + k];
#pragma unroll
    for (int c = 0; c < RJ; ++c) {
      acc[0][c] = fmaf(a0, w[c], acc[0][c]);
      acc[1][c] = fmaf(a1, w[c], acc[1][c]);
      acc[2][c] = fmaf(a2, w[c], acc[2][c]);
      acc[3][c] = fmaf(a3, w[c], acc[3][c]);
    }
  }

  float bv[RJ];
#pragma unroll
  for (int c = 0; c < RJ; ++c) bv[c] = bias[j0 + c];
#pragma unroll
  for (int r = 0; r < 4; ++r) {
    int n = nb + ty * 4 + r;
    if (n < N) {
#pragma unroll
      for (int c = 0; c < RJ; ++c) out[(size_t)n * DOUT + j0 + c] = acc[r][c] + bv[c];
    }
  }
}

// ---------------- BN stats: per-feature sum & sumsq ----------------
template <int D>
__global__ __launch_bounds__(256) void bn_stats(const float* __restrict__ h, int N,
                                                float* __restrict__ sums) {
  int n0 = blockIdx.x * 1024;
  int n1 = min(n0 + 1024, N);
  if constexpr (D <= 256) {
    constexpr int NPB = 256 / D;
    int nl = threadIdx.x / D, f = threadIdx.x % D;
    float s = 0.f, q = 0.f;
    for (int n = n0 + nl; n < n1; n += NPB) {
      float v = h[(size_t)n * D + f];
      s += v; q += v * v;
    }
    atomicAdd(&sums[f], s);
    atomicAdd(&sums[D + f], q);
  } else {
    constexpr int PF = D / 256;
    float s[PF], q[PF];
#pragma unroll
    for (int p = 0; p < PF; ++p) { s[p] = 0.f; q[p] = 0.f; }
    for (int n = n0; n < n1; ++n) {
#pragma unroll
      for (int p = 0; p < PF; ++p) {
        float v = h[(size_t)n * D + threadIdx.x + 256 * p];
        s[p] += v; q[p] += v * v;
      }
    }
#pragma unroll
    for (int p = 0; p < PF; ++p) {
      atomicAdd(&sums[threadIdx.x + 256 * p], s[p]);
      atomicAdd(&sums[D + threadIdx.x + 256 * p], q[p]);
    }
  }
}

// ---------------- BN finalize: a = g*rsqrt(var+eps), b = be - m*a ----------------
template <int D>
__global__ void bn_finalize(const float* __restrict__ sums, const float* __restrict__ g,
                            const float* __restrict__ be, float* __restrict__ ab, float invN) {
  int f = blockIdx.x * blockDim.x + threadIdx.x;
  if (f >= D) return;
  float m = sums[f] * invN;
  float var = sums[D + f] * invN - m * m;
  float a = g[f] * rsqrtf(var + EPSF);
  ab[f] = a;
  ab[D + f] = be[f] - m * a;
}

// ---------------- BN apply + ReLU, in place, float4 ----------------
template <int D>
__global__ __launch_bounds__(256) void bn_apply(float* __restrict__ h,
                                                const float* __restrict__ ab, int total4) {
  int idx = blockIdx.x * 256 + threadIdx.x;
  if (idx >= total4) return;
  float4 v = reinterpret_cast<float4*>(h)[idx];
  int f = (idx % (D / 4)) * 4;
  const float4 A = *reinterpret_cast<const float4*>(&ab[f]);
  const float4 B = *reinterpret_cast<const float4*>(&ab[D + f]);
  v.x = fmaxf(fmaf(v.x, A.x, B.x), 0.f);
  v.y = fmaxf(fmaf(v.y, A.y, B.y), 0.f);
  v.z = fmaxf(fmaf(v.z, A.z, B.z), 0.f);
  v.w = fmaxf(fmaf(v.w, A.w, B.w), 0.f);
  reinterpret_cast<float4*>(h)[idx] = v;
}

// ---------------- global max pool over sorted batch (values >= 0) ----------------
__global__ __launch_bounds__(256) void pool_kernel(const float* __restrict__ h,
                                                   const int* __restrict__ batch,
                                                   float* __restrict__ pooled, int N) {
  const int D = 512;
  const int CH = 512;
  int f = blockIdx.y * 256 + threadIdx.x;
  int n0 = blockIdx.x * CH;
  if (n0 >= N) return;
  int n1 = min(n0 + CH, N);
  int g = batch[n0];
  float m = 0.0f;
  for (int n = n0; n < n1; ++n) {
    int gn = batch[n];
    if (gn != g) {
      atomicMax(reinterpret_cast<unsigned int*>(&pooled[(size_t)g * D + f]),
                __float_as_uint(m));
      g = gn;
      m = 0.0f;
    }
    m = fmaxf(m, h[(size_t)n * D + f]);
  }
  atomicMax(reinterpret_cast<unsigned int*>(&pooled[(size_t)g * D + f]), __float_as_uint(m));
}

// ---------------- MLP head: out = relu(pooled@w1+b1)@w2+b2 ----------------
__global__ __launch_bounds__(256) void head_kernel(const float* __restrict__ pooled,
                                                   const float* __restrict__ w1,
                                                   const float* __restrict__ b1,
                                                   const float* __restrict__ w2,
                                                   const float* __restrict__ b2,
                                                   float* __restrict__ out) {
  __shared__ float pr[512];
  __shared__ float hid[256];
  int g = blockIdx.x;
  int t = threadIdx.x;
  pr[t] = pooled[(size_t)g * 512 + t];
  pr[t + 256] = pooled[(size_t)g * 512 + 256 + t];
  __syncthreads();
  float acc = b1[t];
  for (int i = 0; i < 512; ++i) acc = fmaf(pr[i], w1[(size_t)i * 256 + t], acc);
  hid[t] = fmaxf(acc, 0.f);
  __syncthreads();
  if (t < 10) {
    float o = b2[t];
    for (int j = 0; j < 256; ++j) o = fmaf(hid[j], w2[(size_t)j * 10 + t], o);
    out[(size_t)g * 10 + t] = o;
  }
}

extern "C" void kernel_launch(void* const* d_in, const int* in_sizes, int n_in,
                              void* d_out, int out_size, void* d_ws, size_t ws_size,
                              hipStream_t stream) {
  const float* x    = (const float*)d_in[0];
  const int*   ei   = (const int*)d_in[1];
  const int*   batch= (const int*)d_in[2];
  const float* w1_l = (const float*)d_in[3];
  const float* b1   = (const float*)d_in[4];
  const float* w1_r = (const float*)d_in[5];
  const float* w2_l = (const float*)d_in[6];
  const float* b2   = (const float*)d_in[7];
  const float* w2_r = (const float*)d_in[8];
  const float* w3_l = (const float*)d_in[9];
  const float* b3   = (const float*)d_in[10];
  const float* w3_r = (const float*)d_in[11];
  const float* g1   = (const float*)d_in[12];
  const float* be1  = (const float*)d_in[13];
  const float* g2   = (const float*)d_in[14];
  const float* be2  = (const float*)d_in[15];
  const float* g3   = (const float*)d_in[16];
  const float* be3  = (const float*)d_in[17];
  const float* wl1  = (const float*)d_in[18];
  const float* bl1  = (const float*)d_in[19];
  const float* wl2  = (const float*)d_in[20];
  const float* bl2  = (const float*)d_in[21];

  const int N = in_sizes[0] / 32;
  const int E = in_sizes[1] / 2;
  const int* src  = ei;
  const int* dstp = ei + E;
  float* outp = (float*)d_out;

  size_t off = 0;
  auto alloc = [&](size_t bytes) -> void* {
    void* p = (char*)d_ws + off;
    off += (bytes + 255) & ~(size_t)255;
    return p;
  };
  float* cnt    = (float*)alloc((size_t)N * 4);
  float* agg    = (float*)alloc((size_t)N * 64 * 4);
  float* h1     = (float*)alloc((size_t)N * 16 * 4);
  float* h2     = (float*)alloc((size_t)N * 64 * 4);
  float* h3     = (float*)alloc((size_t)N * 512 * 4);
  float* bnsum  = (float*)alloc(2 * 512 * 4);
  float* bnab   = (float*)alloc(2 * 512 * 4);
  float* pooled = (float*)alloc((size_t)NUM_GRAPHS * 512 * 4);
  (void)ws_size;

  const float invN = 1.0f / (float)N;

  // degree counts (shared by all layers)
  hipMemsetAsync(cnt, 0, (size_t)N * 4, stream);
  count_kernel<<<(E + 255) / 256, 256, 0, stream>>>(dstp, cnt, E);

  // ---------- layer 1: 32 -> 16 ----------
  hipMemsetAsync(agg, 0, (size_t)N * 32 * 4, stream);
  scatter_kernel<32><<<(E * 32 + 255) / 256, 256, 0, stream>>>(x, src, dstp, agg, E);
  linear_kernel<32, 16, 1><<<dim3((N + 63) / 64, 1), 256, 0, stream>>>(
      agg, cnt, x, w1_l, b1, w1_r, h1, N);
  hipMemsetAsync(bnsum, 0, 2 * 16 * 4, stream);
  bn_stats<16><<<(N + 1023) / 1024, 256, 0, stream>>>(h1, N, bnsum);
  bn_finalize<16><<<1, 16, 0, stream>>>(bnsum, g1, be1, bnab, invN);
  bn_apply<16><<<(N * 16 / 4 + 255) / 256, 256, 0, stream>>>(h1, bnab, N * 16 / 4);

  // ---------- layer 2: 16 -> 64 ----------
  hipMemsetAsync(agg, 0, (size_t)N * 16 * 4, stream);
  scatter_kernel<16><<<(E * 16 + 255) / 256, 256, 0, stream>>>(h1, src, dstp, agg, E);
  linear_kernel<16, 64, 4><<<dim3((N + 63) / 64, 1), 256, 0, stream>>>(
      agg, cnt, h1, w2_l, b2, w2_r, h2, N);
  hipMemsetAsync(bnsum, 0, 2 * 64 * 4, stream);
  bn_stats<64><<<(N + 1023) / 1024, 256, 0, stream>>>(h2, N, bnsum);
  bn_finalize<64><<<1, 64, 0, stream>>>(bnsum, g2, be2, bnab, invN);
  bn_apply<64><<<(N * 64 / 4 + 255) / 256, 256, 0, stream>>>(h2, bnab, N * 64 / 4);

  // ---------- layer 3: 64 -> 512 ----------
  hipMemsetAsync(agg, 0, (size_t)N * 64 * 4, stream);
  scatter_kernel<64><<<(E * 64 + 255) / 256, 256, 0, stream>>>(h2, src, dstp, agg, E);
  linear_kernel<64, 512, 8><<<dim3((N + 63) / 64, 4), 256, 0, stream>>>(
      agg, cnt, h2, w3_l, b3, w3_r, h3, N);
  hipMemsetAsync(bnsum, 0, 2 * 512 * 4, stream);
  bn_stats<512><<<(N + 1023) / 1024, 256, 0, stream>>>(h3, N, bnsum);
  bn_finalize<512><<<1, 512, 0, stream>>>(bnsum, g3, be3, bnab, invN);
  bn_apply<512><<<(N * 512 / 4 + 255) / 256, 256, 0, stream>>>(h3, bnab, N * 512 / 4);

  // ---------- pool + head ----------
  hipMemsetAsync(pooled, 0, (size_t)NUM_GRAPHS * 512 * 4, stream);
  pool_kernel<<<dim3((N + 511) / 512, 2), 256, 0, stream>>>(h3, batch, pooled, N);
  head_kernel<<<NUM_GRAPHS, 256, 0, stream>>>(pooled, wl1, bl1, wl2, bl2, outp);
}

// Round 2
// 1156.132 us; speedup vs baseline: 1.4808x; 1.4808x over previous
//
#include <hip/hip_runtime.h>
#include <hip/hip_bf16.h>
#include <cstdint>

#define NUM_GRAPHS 128
constexpr float EPSF = 1e-5f;

// ---------------- count incoming edges per node ----------------
__global__ __launch_bounds__(256) void count_kernel(const int* __restrict__ dst,
                                                    float* __restrict__ cnt, int E) {
  int e = blockIdx.x * 256 + threadIdx.x;
  if (e < E) atomicAdd(&cnt[dst[e]], 1.0f);
}

// ---------------- edge scatter: agg[dst] += f(h[src])  (D = pow2) ----------------
// BN=true: apply relu(a*v+b) with a,b from ab[] (post-BN message space).
template <int D, bool BN>
__global__ __launch_bounds__(256) void scatter_kernel(const float* __restrict__ h,
                                                      const int* __restrict__ src,
                                                      const int* __restrict__ dst,
                                                      const float* __restrict__ ab,
                                                      float* __restrict__ agg, int E) {
  int idx = blockIdx.x * 256 + threadIdx.x;
  if (idx >= E * D) return;
  int e = idx / D;
  int f = idx & (D - 1);
  float v = h[(size_t)src[e] * D + f];
  if (BN) v = fmaxf(fmaf(v, ab[f], ab[D + f]), 0.f);
  atomicAdd(&agg[(size_t)dst[e] * D + f], v);
}

// ---------------- weight vector load ----------------
template <int RJ>
__device__ __forceinline__ void loadw(const float* __restrict__ p, float* w) {
  if constexpr (RJ == 1) {
    w[0] = p[0];
  } else if constexpr (RJ == 4) {
    const float4 v = *reinterpret_cast<const float4*>(p);
    w[0] = v.x; w[1] = v.y; w[2] = v.z; w[3] = v.w;
  } else {
    const float4 v0 = *reinterpret_cast<const float4*>(p);
    const float4 v1 = *reinterpret_cast<const float4*>(p + 4);
    w[0] = v0.x; w[1] = v0.y; w[2] = v0.z; w[3] = v0.w;
    w[4] = v1.x; w[5] = v1.y; w[6] = v1.z; w[7] = v1.w;
  }
}

// ---------------- node linear: out = (agg/max(cnt,1)) @ wl + b + bn_in(x) @ wr ----------------
// block = 256 threads = 16(ty, node) x 16(tx, j). Tile: 64 nodes x (16*RJ) outputs.
// Fused: BN transform of the root input (BNIN), and BN-stats (sum/sumsq) of the output.
template <int DIN, int DOUT, int RJ, bool BNIN>
__global__ __launch_bounds__(256) void linear_kernel(
    const float* __restrict__ agg, const float* __restrict__ cnt,
    const float* __restrict__ xin, const float* __restrict__ wl,
    const float* __restrict__ bias, const float* __restrict__ wr,
    const float* __restrict__ ab_in, float* __restrict__ out,
    float* __restrict__ bnsum_out, int N) {
  constexpr int K2P = 2 * DIN + 1;  // mean | x rows, +1 pad
  __shared__ float As[64 * K2P];
  const int nb = blockIdx.x * 64;
  const int tid = threadIdx.x;

  for (int idx = tid; idx < 64 * DIN; idx += 256) {
    int nl = idx / DIN, k = idx % DIN;
    int n = nb + nl;
    float mv = 0.f, xv = 0.f;
    if (n < N) {
      float c = fmaxf(cnt[n], 1.0f);
      mv = agg[(size_t)n * DIN + k] / c;
      xv = xin[(size_t)n * DIN + k];
      if (BNIN) xv = fmaxf(fmaf(xv, ab_in[k], ab_in[DIN + k]), 0.f);
    }
    As[nl * K2P + k] = mv;
    As[nl * K2P + DIN + k] = xv;
  }
  __syncthreads();

  const int ty = tid >> 4, tx = tid & 15;
  const int j0 = blockIdx.y * (16 * RJ) + tx * RJ;
  float acc[4][RJ];
#pragma unroll
  for (int r = 0; r < 4; ++r)
#pragma unroll
    for (int c = 0; c < RJ; ++c) acc[r][c] = 0.f;

  const float* A0 = &As[(ty * 4 + 0) * K2P];
  const float* A1 = &As[(ty * 4 + 1) * K2P];
  const float* A2 = &As[(ty * 4 + 2) * K2P];
  const float* A3 = &As[(ty * 4 + 3) * K2P];

#pragma unroll 4
  for (int k = 0; k < DIN; ++k) {  // mean part
    float w[RJ];
    loadw<RJ>(wl + (size_t)k * DOUT + j0, w);
    float a0 = A0[k], a1 = A1[k], a2 = A2[k], a3 = A3[k];
#pragma unroll
    for (int c = 0; c < RJ; ++c) {
      acc[0][c] = fmaf(a0, w[c], acc[0][c]);
      acc[1][c] = fmaf(a1, w[c], acc[1][c]);
      acc[2][c] = fmaf(a2, w[c], acc[2][c]);
      acc[3][c] = fmaf(a3, w[c], acc[3][c]);
    }
  }
#pragma unroll 4
  for (int k = 0; k < DIN; ++k) {  // root part
    float w[RJ];
    loadw<RJ>(wr + (size_t)k * DOUT + j0, w);
    float a0 = A0[DIN + k], a1 = A1[DIN + k], a2 = A2[DIN + k], a3 = A3[DIN + k];
#pragma unroll
    for (int c = 0; c < RJ; ++c) {
      acc[0][c] = fmaf(a0, w[c], acc[0][c]);
      acc[1][c] = fmaf(a1, w[c], acc[1][c]);
      acc[2][c] = fmaf(a2, w[c], acc[2][c]);
      acc[3][c] = fmaf(a3, w[c], acc[3][c]);
    }
  }

  float bv[RJ];
#pragma unroll
  for (int c = 0; c < RJ; ++c) bv[c] = bias[j0 + c];

  // write outputs + per-thread stats
  float s[RJ], q[RJ];
#pragma unroll
  for (int c = 0; c < RJ; ++c) { s[c] = 0.f; q[c] = 0.f; }
#pragma unroll
  for (int r = 0; r < 4; ++r) {
    int n = nb + ty * 4 + r;
    if (n < N) {
#pragma unroll
      for (int c = 0; c < RJ; ++c) {
        float v = acc[r][c] + bv[c];
        out[(size_t)n * DOUT + j0 + c] = v;
        s[c] += v;
        q[c] += v * v;
      }
    }
  }

  // block-level reduce of stats in LDS (reuse As), then one atomic per feature
  constexpr int F = 16 * RJ;  // features covered by this block
  __syncthreads();
  float* sL = As;
  float* qL = As + 16 * F;
#pragma unroll
  for (int c = 0; c < RJ; ++c) {
    sL[ty * F + tx * RJ + c] = s[c];
    qL[ty * F + tx * RJ + c] = q[c];
  }
  __syncthreads();
  for (int f = tid; f < F; f += 256) {
    float ss = 0.f, qq = 0.f;
#pragma unroll
    for (int t = 0; t < 16; ++t) { ss += sL[t * F + f]; qq += qL[t * F + f]; }
    atomicAdd(&bnsum_out[blockIdx.y * F + f], ss);
    atomicAdd(&bnsum_out[DOUT + blockIdx.y * F + f], qq);
  }
}

// ---------------- BN finalize: a = g*rsqrt(var+eps), b = be - m*a ----------------
template <int D>
__global__ void bn_finalize(const float* __restrict__ sums, const float* __restrict__ g,
                            const float* __restrict__ be, float* __restrict__ ab, float invN) {
  int f = blockIdx.x * blockDim.x + threadIdx.x;
  if (f >= D) return;
  float m = sums[f] * invN;
  float var = sums[D + f] * invN - m * m;
  float a = g[f] * rsqrtf(var + EPSF);
  ab[f] = a;
  ab[D + f] = be[f] - m * a;
}

// ---------------- fused BN+ReLU+global max pool (sorted batch, relu => >= 0) --------
__global__ __launch_bounds__(256) void bnpool_kernel(const float* __restrict__ h,
                                                     const float* __restrict__ ab,
                                                     const int* __restrict__ batch,
                                                     float* __restrict__ pooled, int N) {
  const int D = 512;
  const int CH = 256;
  int f = blockIdx.y * 256 + threadIdx.x;
  int n0 = blockIdx.x * CH;
  if (n0 >= N) return;
  int n1 = min(n0 + CH, N);
  const float a = ab[f], b = ab[D + f];
  int g = batch[n0];
  float m = 0.0f;
  for (int n = n0; n < n1; ++n) {
    int gn = batch[n];
    if (gn != g) {
      atomicMax(reinterpret_cast<unsigned int*>(&pooled[(size_t)g * D + f]),
                __float_as_uint(m));
      g = gn;
      m = 0.0f;
    }
    m = fmaxf(m, fmaf(h[(size_t)n * D + f], a, b));
  }
  atomicMax(reinterpret_cast<unsigned int*>(&pooled[(size_t)g * D + f]), __float_as_uint(m));
}

// ---------------- MLP head: out = relu(pooled@w1+b1)@w2+b2 ----------------
__global__ __launch_bounds__(256) void head_kernel(const float* __restrict__ pooled,
                                                   const float* __restrict__ w1,
                                                   const float* __restrict__ b1,
                                                   const float* __restrict__ w2,
                                                   const float* __restrict__ b2,
                                                   float* __restrict__ out) {
  __shared__ float pr[512];
  __shared__ float hid[256];
  int g = blockIdx.x;
  int t = threadIdx.x;
  pr[t] = pooled[(size_t)g * 512 + t];
  pr[t + 256] = pooled[(size_t)g * 512 + 256 + t];
  __syncthreads();
  float acc = b1[t];
  for (int i = 0; i < 512; ++i) acc = fmaf(pr[i], w1[(size_t)i * 256 + t], acc);
  hid[t] = fmaxf(acc, 0.f);
  __syncthreads();
  if (t < 10) {
    float o = b2[t];
    for (int j = 0; j < 256; ++j) o = fmaf(hid[j], w2[(size_t)j * 10 + t], o);
    out[(size_t)g * 10 + t] = o;
  }
}

extern "C" void kernel_launch(void* const* d_in, const int* in_sizes, int n_in,
                              void* d_out, int out_size, void* d_ws, size_t ws_size,
                              hipStream_t stream) {
  const float* x    = (const float*)d_in[0];
  const int*   ei   = (const int*)d_in[1];
  const int*   batch= (const int*)d_in[2];
  const float* w1_l = (const float*)d_in[3];
  const float* b1   = (const float*)d_in[4];
  const float* w1_r = (const float*)d_in[5];
  const float* w2_l = (const float*)d_in[6];
  const float* b2   = (const float*)d_in[7];
  const float* w2_r = (const float*)d_in[8];
  const float* w3_l = (const float*)d_in[9];
  const float* b3   = (const float*)d_in[10];
  const float* w3_r = (const float*)d_in[11];
  const float* g1   = (const float*)d_in[12];
  const float* be1  = (const float*)d_in[13];
  const float* g2   = (const float*)d_in[14];
  const float* be2  = (const float*)d_in[15];
  const float* g3   = (const float*)d_in[16];
  const float* be3  = (const float*)d_in[17];
  const float* wl1  = (const float*)d_in[18];
  const float* bl1  = (const float*)d_in[19];
  const float* wl2  = (const float*)d_in[20];
  const float* bl2  = (const float*)d_in[21];

  const int N = in_sizes[0] / 32;
  const int E = in_sizes[1] / 2;
  const int* src  = ei;
  const int* dstp = ei + E;
  float* outp = (float*)d_out;

  size_t off = 0;
  auto alloc = [&](size_t bytes) -> void* {
    void* p = (char*)d_ws + off;
    off += (bytes + 255) & ~(size_t)255;
    return p;
  };
  float* cnt    = (float*)alloc((size_t)N * 4);
  float* agg    = (float*)alloc((size_t)N * 64 * 4);
  float* h1     = (float*)alloc((size_t)N * 16 * 4);
  float* h2     = (float*)alloc((size_t)N * 64 * 4);
  float* h3     = (float*)alloc((size_t)N * 512 * 4);
  float* bnsum1 = (float*)alloc(2 * 16 * 4);
  float* bnsum2 = (float*)alloc(2 * 64 * 4);
  float* bnsum3 = (float*)alloc(2 * 512 * 4);
  float* bnab1  = (float*)alloc(2 * 16 * 4);
  float* bnab2  = (float*)alloc(2 * 64 * 4);
  float* bnab3  = (float*)alloc(2 * 512 * 4);
  float* pooled = (float*)alloc((size_t)NUM_GRAPHS * 512 * 4);
  (void)ws_size;

  const float invN = 1.0f / (float)N;

  // degree counts (shared by all layers)
  hipMemsetAsync(cnt, 0, (size_t)N * 4, stream);
  count_kernel<<<(E + 255) / 256, 256, 0, stream>>>(dstp, cnt, E);

  // ---------- layer 1: 32 -> 16 (input x is raw, no BN) ----------
  hipMemsetAsync(agg, 0, (size_t)N * 32 * 4, stream);
  hipMemsetAsync(bnsum1, 0, 2 * 16 * 4, stream);
  scatter_kernel<32, false><<<(E * 32 + 255) / 256, 256, 0, stream>>>(
      x, src, dstp, nullptr, agg, E);
  linear_kernel<32, 16, 1, false><<<dim3((N + 63) / 64, 1), 256, 0, stream>>>(
      agg, cnt, x, w1_l, b1, w1_r, nullptr, h1, bnsum1, N);
  bn_finalize<16><<<1, 16, 0, stream>>>(bnsum1, g1, be1, bnab1, invN);

  // ---------- layer 2: 16 -> 64 (BN1+ReLU applied on the fly to h1) ----------
  hipMemsetAsync(agg, 0, (size_t)N * 16 * 4, stream);
  hipMemsetAsync(bnsum2, 0, 2 * 64 * 4, stream);
  scatter_kernel<16, true><<<(E * 16 + 255) / 256, 256, 0, stream>>>(
      h1, src, dstp, bnab1, agg, E);
  linear_kernel<16, 64, 4, true><<<dim3((N + 63) / 64, 1), 256, 0, stream>>>(
      agg, cnt, h1, w2_l, b2, w2_r, bnab1, h2, bnsum2, N);
  bn_finalize<64><<<1, 64, 0, stream>>>(bnsum2, g2, be2, bnab2, invN);

  // ---------- layer 3: 64 -> 512 (BN2+ReLU applied on the fly to h2) ----------
  hipMemsetAsync(agg, 0, (size_t)N * 64 * 4, stream);
  hipMemsetAsync(bnsum3, 0, 2 * 512 * 4, stream);
  scatter_kernel<64, true><<<(E * 64 + 255) / 256, 256, 0, stream>>>(
      h2, src, dstp, bnab2, agg, E);
  linear_kernel<64, 512, 8, true><<<dim3((N + 63) / 64, 4), 256, 0, stream>>>(
      agg, cnt, h2, w3_l, b3, w3_r, bnab2, h3, bnsum3, N);
  bn_finalize<512><<<1, 512, 0, stream>>>(bnsum3, g3, be3, bnab3, invN);

  // ---------- fused BN3+ReLU+pool, then head ----------
  hipMemsetAsync(pooled, 0, (size_t)NUM_GRAPHS * 512 * 4, stream);
  bnpool_kernel<<<dim3((N + 255) / 256, 2), 256, 0, stream>>>(h3, bnab3, batch, pooled, N);
  head_kernel<<<NUM_GRAPHS, 256, 0, stream>>>(pooled, wl1, bl1, wl2, bl2, outp);
}

// Round 4
// 697.357 us; speedup vs baseline: 2.4550x; 1.6579x over previous
//
#include <hip/hip_runtime.h>
#include <hip/hip_bf16.h>
#include <cstdint>

#define NUM_GRAPHS 128
constexpr float EPSF = 1e-5f;

// order-preserving float<->uint key (works for negatives); max-identity key = 0x007FFFFF (-inf),
// min-identity key = 0xFF800000 (+inf)
__device__ __forceinline__ unsigned int enc_key(float f) {
  unsigned int b = __float_as_uint(f);
  return (b & 0x80000000u) ? ~b : (b | 0x80000000u);
}
__device__ __forceinline__ float dec_key(unsigned int k) {
  return __uint_as_float((k & 0x80000000u) ? (k ^ 0x80000000u) : ~k);
}

// ================= CSR build =================
__global__ __launch_bounds__(256) void deg_kernel(const int* __restrict__ dst,
                                                  int* __restrict__ deg, int E) {
  int e = blockIdx.x * 256 + threadIdx.x;
  if (e < E) atomicAdd(&deg[dst[e]], 1);
}

__global__ __launch_bounds__(256) void scan1_kernel(const int* __restrict__ deg,
                                                    int* __restrict__ excl,
                                                    int* __restrict__ bsum, int N) {
  __shared__ int ts[256];
  const int base = blockIdx.x * 2048;
  const int tid = threadIdx.x;
  int v[8];
  int tsum = 0;
  const int tb = base + tid * 8;
#pragma unroll
  for (int j = 0; j < 8; ++j) {
    int idx = tb + j;
    v[j] = (idx < N) ? deg[idx] : 0;
    tsum += v[j];
  }
  ts[tid] = tsum;
  __syncthreads();
  for (int off = 1; off < 256; off <<= 1) {
    int add = (tid >= off) ? ts[tid - off] : 0;
    __syncthreads();
    ts[tid] += add;
    __syncthreads();
  }
  int run = ts[tid] - tsum;
#pragma unroll
  for (int j = 0; j < 8; ++j) {
    int idx = tb + j;
    if (idx < N) excl[idx] = run;
    run += v[j];
  }
  if (tid == 255) bsum[blockIdx.x] = ts[255];
}

__global__ void scan2_kernel(int* __restrict__ bsum, int nb) {
  if (threadIdx.x == 0 && blockIdx.x == 0) {
    int run = 0;
    for (int i = 0; i < nb; ++i) { int t = bsum[i]; bsum[i] = run; run += t; }
  }
}

__global__ __launch_bounds__(256) void scan3_kernel(const int* __restrict__ bsum,
                                                    int* __restrict__ rowptr,
                                                    int* __restrict__ cursor,
                                                    int N, int E) {
  int i = blockIdx.x * 256 + threadIdx.x;
  if (i < N) {
    int v = rowptr[i] + bsum[i >> 11];
    rowptr[i] = v;
    cursor[i] = v;
  }
  if (i == 0) rowptr[N] = E;
}

__global__ __launch_bounds__(256) void fill_kernel(const int* __restrict__ src,
                                                   const int* __restrict__ dst,
                                                   int* __restrict__ cursor,
                                                   int* __restrict__ csr, int E) {
  int e = blockIdx.x * 256 + threadIdx.x;
  if (e < E) {
    int pos = atomicAdd(&cursor[dst[e]], 1);
    csr[pos] = src[e];
  }
}

// ================= pooled-key init =================
__global__ __launch_bounds__(256) void pool_init_kernel(unsigned int* __restrict__ pmax,
                                                        unsigned int* __restrict__ pmin, int n) {
  int i = blockIdx.x * 256 + threadIdx.x;
  if (i < n) { pmax[i] = 0x007FFFFFu; pmin[i] = 0xFF800000u; }
}

// ================= standalone gather-mean (layer 3) =================
template <int DIN, bool BN>
__global__ __launch_bounds__(256) void gather_mean_kernel(
    const float* __restrict__ h, const int* __restrict__ rowptr,
    const int* __restrict__ csr, const float* __restrict__ ab,
    float* __restrict__ mean, int N) {
  constexpr int NF4 = DIN / 16;
  const int tid = threadIdx.x;
  const int nl = tid >> 2, t = tid & 3;
  const int n = blockIdx.x * 64 + nl;
  if (n >= N) return;
  float4 acc[NF4];
#pragma unroll
  for (int i = 0; i < NF4; ++i) acc[i] = make_float4(0.f, 0.f, 0.f, 0.f);
  float4 a4[NF4], b4[NF4];
  if (BN) {
#pragma unroll
    for (int i = 0; i < NF4; ++i) {
      a4[i] = *reinterpret_cast<const float4*>(&ab[(t + 4 * i) * 4]);
      b4[i] = *reinterpret_cast<const float4*>(&ab[DIN + (t + 4 * i) * 4]);
    }
  }
  const int r0 = rowptr[n], r1 = rowptr[n + 1];
  for (int p = r0; p < r1; ++p) {
    const float4* row = reinterpret_cast<const float4*>(h + (size_t)csr[p] * DIN);
#pragma unroll
    for (int i = 0; i < NF4; ++i) {
      float4 v = row[t + 4 * i];
      if (BN) {
        v.x = fmaxf(fmaf(v.x, a4[i].x, b4[i].x), 0.f);
        v.y = fmaxf(fmaf(v.y, a4[i].y, b4[i].y), 0.f);
        v.z = fmaxf(fmaf(v.z, a4[i].z, b4[i].z), 0.f);
        v.w = fmaxf(fmaf(v.w, a4[i].w, b4[i].w), 0.f);
      }
      acc[i].x += v.x; acc[i].y += v.y; acc[i].z += v.z; acc[i].w += v.w;
    }
  }
  const float sc = 1.0f / fmaxf((float)(r1 - r0), 1.0f);
  float4* mrow = reinterpret_cast<float4*>(mean + (size_t)n * DIN);
#pragma unroll
  for (int i = 0; i < NF4; ++i) {
    float4 o;
    o.x = acc[i].x * sc; o.y = acc[i].y * sc; o.z = acc[i].z * sc; o.w = acc[i].w * sc;
    mrow[t + 4 * i] = o;
  }
}

// ================= weight vector load =================
template <int RJ>
__device__ __forceinline__ void loadw(const float* __restrict__ p, float* w) {
  if constexpr (RJ == 1) {
    w[0] = p[0];
  } else if constexpr (RJ == 4) {
    const float4 v = *reinterpret_cast<const float4*>(p);
    w[0] = v.x; w[1] = v.y; w[2] = v.z; w[3] = v.w;
  } else {
    const float4 v0 = *reinterpret_cast<const float4*>(p);
    const float4 v1 = *reinterpret_cast<const float4*>(p + 4);
    w[0] = v0.x; w[1] = v0.y; w[2] = v0.z; w[3] = v0.w;
    w[4] = v1.x; w[5] = v1.y; w[6] = v1.z; w[7] = v1.w;
  }
}

// ================= fused node linear =================
// out = mean @ wl + b + bn_in(x) @ wr. Epilogue: BN stats always; if POOL, pre-BN
// per-(graph,feature) max/min pooling instead of writing out.
template <int DIN, int DOUT, int RJ, bool BNIN, bool PREMEAN, bool POOL>
__global__ __launch_bounds__(256) void linear_kernel(
    const float* __restrict__ mean_pre, const int* __restrict__ rowptr,
    const int* __restrict__ csr, const float* __restrict__ xin,
    const float* __restrict__ wl, const float* __restrict__ bias,
    const float* __restrict__ wr, const float* __restrict__ ab_in,
    float* __restrict__ out, float* __restrict__ bnsum_out,
    const int* __restrict__ batchp, unsigned int* __restrict__ pmax,
    unsigned int* __restrict__ pmin, int N) {
  constexpr int K2P = 2 * DIN + 1;
  __shared__ float As[64 * K2P];
  __shared__ int gb[64];
  const int nb = blockIdx.x * 64;
  const int tid = threadIdx.x;

  if constexpr (!PREMEAN) {
    constexpr int NF4 = DIN / 16;
    const int nl = tid >> 2, t = tid & 3;
    const int n = nb + nl;
    float4 acc[NF4];
#pragma unroll
    for (int i = 0; i < NF4; ++i) acc[i] = make_float4(0.f, 0.f, 0.f, 0.f);
    float sc = 0.f;
    if (n < N) {
      float4 a4[NF4], b4[NF4];
      if (BNIN) {
#pragma unroll
        for (int i = 0; i < NF4; ++i) {
          a4[i] = *reinterpret_cast<const float4*>(&ab_in[(t + 4 * i) * 4]);
          b4[i] = *reinterpret_cast<const float4*>(&ab_in[DIN + (t + 4 * i) * 4]);
        }
      }
      const int r0 = rowptr[n], r1 = rowptr[n + 1];
      for (int p = r0; p < r1; ++p) {
        const float4* row = reinterpret_cast<const float4*>(xin + (size_t)csr[p] * DIN);
#pragma unroll
        for (int i = 0; i < NF4; ++i) {
          float4 v = row[t + 4 * i];
          if (BNIN) {
            v.x = fmaxf(fmaf(v.x, a4[i].x, b4[i].x), 0.f);
            v.y = fmaxf(fmaf(v.y, a4[i].y, b4[i].y), 0.f);
            v.z = fmaxf(fmaf(v.z, a4[i].z, b4[i].z), 0.f);
            v.w = fmaxf(fmaf(v.w, a4[i].w, b4[i].w), 0.f);
          }
          acc[i].x += v.x; acc[i].y += v.y; acc[i].z += v.z; acc[i].w += v.w;
        }
      }
      sc = 1.0f / fmaxf((float)(r1 - r0), 1.0f);
    }
#pragma unroll
    for (int i = 0; i < NF4; ++i) {
      int f = (t + 4 * i) * 4;
      As[nl * K2P + f + 0] = acc[i].x * sc;
      As[nl * K2P + f + 1] = acc[i].y * sc;
      As[nl * K2P + f + 2] = acc[i].z * sc;
      As[nl * K2P + f + 3] = acc[i].w * sc;
    }
  } else {
    constexpr int R4 = DIN / 4;
    for (int idx4 = tid; idx4 < 64 * R4; idx4 += 256) {
      int nl = idx4 / R4, k4 = idx4 % R4;
      int n = nb + nl;
      float4 v = make_float4(0.f, 0.f, 0.f, 0.f);
      if (n < N) v = reinterpret_cast<const float4*>(mean_pre + (size_t)n * DIN)[k4];
      As[nl * K2P + k4 * 4 + 0] = v.x;
      As[nl * K2P + k4 * 4 + 1] = v.y;
      As[nl * K2P + k4 * 4 + 2] = v.z;
      As[nl * K2P + k4 * 4 + 3] = v.w;
    }
  }

  {
    constexpr int R4 = DIN / 4;
    for (int idx4 = tid; idx4 < 64 * R4; idx4 += 256) {
      int nl = idx4 / R4, k4 = idx4 % R4;
      int n = nb + nl;
      float4 v = make_float4(0.f, 0.f, 0.f, 0.f);
      if (n < N) {
        v = reinterpret_cast<const float4*>(xin + (size_t)n * DIN)[k4];
        if (BNIN) {
          const float4 A = *reinterpret_cast<const float4*>(&ab_in[k4 * 4]);
          const float4 B = *reinterpret_cast<const float4*>(&ab_in[DIN + k4 * 4]);
          v.x = fmaxf(fmaf(v.x, A.x, B.x), 0.f);
          v.y = fmaxf(fmaf(v.y, A.y, B.y), 0.f);
          v.z = fmaxf(fmaf(v.z, A.z, B.z), 0.f);
          v.w = fmaxf(fmaf(v.w, A.w, B.w), 0.f);
        }
      }
      As[nl * K2P + DIN + k4 * 4 + 0] = v.x;
      As[nl * K2P + DIN + k4 * 4 + 1] = v.y;
      As[nl * K2P + DIN + k4 * 4 + 2] = v.z;
      As[nl * K2P + DIN + k4 * 4 + 3] = v.w;
    }
  }
  if constexpr (POOL) {
    if (tid < 64) gb[tid] = (nb + tid < N) ? batchp[nb + tid] : 0x7FFFFFFF;
  }
  __syncthreads();

  const int ty = tid >> 4, tx = tid & 15;
  const int j0 = blockIdx.y * (16 * RJ) + tx * RJ;
  float acc[4][RJ];
#pragma unroll
  for (int r = 0; r < 4; ++r)
#pragma unroll
    for (int c = 0; c < RJ; ++c) acc[r][c] = 0.f;

  const float* A0 = &As[(ty * 4 + 0) * K2P];
  const float* A1 = &As[(ty * 4 + 1) * K2P];
  const float* A2 = &As[(ty * 4 + 2) * K2P];
  const float* A3 = &As[(ty * 4 + 3) * K2P];

#pragma unroll 4
  for (int k = 0; k < DIN; ++k) {
    float w[RJ];
    loadw<RJ>(wl + (size_t)k * DOUT + j0, w);
    float a0 = A0[k], a1 = A1[k], a2 = A2[k], a3 = A3[k];
#pragma unroll
    for (int c = 0; c < RJ; ++c) {
      acc[0][c] = fmaf(a0, w[c], acc[0][c]);
      acc[1][c] = fmaf(a1, w[c], acc[1][c]);
      acc[2][c] = fmaf(a2, w[c], acc[2][c]);
      acc[3][c] = fmaf(a3, w[c], acc[3][c]);
    }
  }
#pragma unroll 4
  for (int k = 0; k < DIN; ++k) {
    float w[RJ];
    loadw<RJ>(wr + (size_t)k * DOUT + j0, w);
    float a0 = A0[DIN + k], a1 = A1[DIN + k], a2 = A2[DIN + k], a3 = A3[DIN + k];
#pragma unroll
    for (int c = 0; c < RJ; ++c) {
      acc[0][c] = fmaf(a0, w[c], acc[0][c]);
      acc[1][c] = fmaf(a1, w[c], acc[1][c]);
      acc[2][c] = fmaf(a2, w[c], acc[2][c]);
      acc[3][c] = fmaf(a3, w[c], acc[3][c]);
    }
  }

  float bv[RJ];
#pragma unroll
  for (int c = 0; c < RJ; ++c) bv[c] = bias[j0 + c];

  float s[RJ], q[RJ];
#pragma unroll
  for (int c = 0; c < RJ; ++c) { s[c] = 0.f; q[c] = 0.f; }
#pragma unroll
  for (int r = 0; r < 4; ++r) {
    int n = nb + ty * 4 + r;
    if (n < N) {
#pragma unroll
      for (int c = 0; c < RJ; ++c) {
        float v = acc[r][c] + bv[c];
        acc[r][c] = v;
        if constexpr (!POOL) out[(size_t)n * DOUT + j0 + c] = v;
        s[c] += v;
        q[c] += v * v;
      }
    }
  }

  constexpr int F = 16 * RJ;
  __syncthreads();
  float* sL = As;
  float* qL = As + 16 * F;
#pragma unroll
  for (int c = 0; c < RJ; ++c) {
    sL[ty * F + tx * RJ + c] = s[c];
    qL[ty * F + tx * RJ + c] = q[c];
  }
  __syncthreads();
  for (int f = tid; f < F; f += 256) {
    float ss = 0.f, qq = 0.f;
#pragma unroll
    for (int t = 0; t < 16; ++t) { ss += sL[t * F + f]; qq += qL[t * F + f]; }
    atomicAdd(&bnsum_out[blockIdx.y * F + f], ss);
    atomicAdd(&bnsum_out[DOUT + blockIdx.y * F + f], qq);
  }

  if constexpr (POOL) {
    __syncthreads();  // done with sL/qL; reuse As for pool partials
    const bool uni = (gb[0] == gb[63]);
    if (uni) {
      const int g0 = gb[0];
      float* mL = As;
      float* nL = As + 16 * F;
#pragma unroll
      for (int c = 0; c < RJ; ++c) {
        float mx = fmaxf(fmaxf(acc[0][c], acc[1][c]), fmaxf(acc[2][c], acc[3][c]));
        float mn = fminf(fminf(acc[0][c], acc[1][c]), fminf(acc[2][c], acc[3][c]));
        mL[ty * F + tx * RJ + c] = mx;
        nL[ty * F + tx * RJ + c] = mn;
      }
      __syncthreads();
      for (int f = tid; f < F; f += 256) {
        float mx = mL[f], mn = nL[f];
#pragma unroll
        for (int t = 1; t < 16; ++t) { mx = fmaxf(mx, mL[t * F + f]); mn = fminf(mn, nL[t * F + f]); }
        atomicMax(&pmax[(size_t)g0 * DOUT + blockIdx.y * F + f], enc_key(mx));
        atomicMin(&pmin[(size_t)g0 * DOUT + blockIdx.y * F + f], enc_key(mn));
      }
    } else {
      // segmented fallback (graph boundary / tail block)
      float rmx[RJ], rmn[RJ];
      int curg = -1;
#pragma unroll
      for (int r = 0; r < 4; ++r) {
        int g = gb[ty * 4 + r];
        if (g != curg) {
          if (curg >= 0 && curg != 0x7FFFFFFF) {
#pragma unroll
            for (int c = 0; c < RJ; ++c) {
              atomicMax(&pmax[(size_t)curg * DOUT + j0 + c], enc_key(rmx[c]));
              atomicMin(&pmin[(size_t)curg * DOUT + j0 + c], enc_key(rmn[c]));
            }
          }
          curg = g;
#pragma unroll
          for (int c = 0; c < RJ; ++c) { rmx[c] = -INFINITY; rmn[c] = INFINITY; }
        }
        if (g != 0x7FFFFFFF) {
#pragma unroll
          for (int c = 0; c < RJ; ++c) {
            rmx[c] = fmaxf(rmx[c], acc[r][c]);
            rmn[c] = fminf(rmn[c], acc[r][c]);
          }
        }
      }
      if (curg >= 0 && curg != 0x7FFFFFFF) {
#pragma unroll
        for (int c = 0; c < RJ; ++c) {
          atomicMax(&pmax[(size_t)curg * DOUT + j0 + c], enc_key(rmx[c]));
          atomicMin(&pmin[(size_t)curg * DOUT + j0 + c], enc_key(rmn[c]));
        }
      }
    }
  }
}

// ================= BN finalize =================
template <int D>
__global__ void bn_finalize(const float* __restrict__ sums, const float* __restrict__ g,
                            const float* __restrict__ be, float* __restrict__ ab, float invN) {
  int f = blockIdx.x * blockDim.x + threadIdx.x;
  if (f >= D) return;
  float m = sums[f] * invN;
  float var = sums[D + f] * invN - m * m;
  float a = g[f] * rsqrtf(var + EPSF);
  ab[f] = a;
  ab[D + f] = be[f] - m * a;
}

// ================= MLP head (decodes pooled keys, applies BN3+ReLU) =================
__global__ __launch_bounds__(256) void head_kernel(const unsigned int* __restrict__ pmax,
                                                   const unsigned int* __restrict__ pmin,
                                                   const float* __restrict__ ab,
                                                   const float* __restrict__ w1,
                                                   const float* __restrict__ b1,
                                                   const float* __restrict__ w2,
                                                   const float* __restrict__ b2,
                                                   float* __restrict__ out) {
  __shared__ float pr[512];
  __shared__ float hid[256];
  int g = blockIdx.x;
  int t = threadIdx.x;
  for (int i = t; i < 512; i += 256) {
    float a = ab[i], b = ab[512 + i];
    float v = (a >= 0.f) ? dec_key(pmax[(size_t)g * 512 + i])
                         : dec_key(pmin[(size_t)g * 512 + i]);
    pr[i] = fmaxf(fmaf(v, a, b), 0.f);
  }
  __syncthreads();
  float acc = b1[t];
  for (int i = 0; i < 512; ++i) acc = fmaf(pr[i], w1[(size_t)i * 256 + t], acc);
  hid[t] = fmaxf(acc, 0.f);
  __syncthreads();
  if (t < 10) {
    float o = b2[t];
    for (int j = 0; j < 256; ++j) o = fmaf(hid[j], w2[(size_t)j * 10 + t], o);
    out[(size_t)g * 10 + t] = o;
  }
}

extern "C" void kernel_launch(void* const* d_in, const int* in_sizes, int n_in,
                              void* d_out, int out_size, void* d_ws, size_t ws_size,
                              hipStream_t stream) {
  const float* x    = (const float*)d_in[0];
  const int*   ei   = (const int*)d_in[1];
  const int*   batch= (const int*)d_in[2];
  const float* w1_l = (const float*)d_in[3];
  const float* b1   = (const float*)d_in[4];
  const float* w1_r = (const float*)d_in[5];
  const float* w2_l = (const float*)d_in[6];
  const float* b2   = (const float*)d_in[7];
  const float* w2_r = (const float*)d_in[8];
  const float* w3_l = (const float*)d_in[9];
  const float* b3   = (const float*)d_in[10];
  const float* w3_r = (const float*)d_in[11];
  const float* g1   = (const float*)d_in[12];
  const float* be1  = (const float*)d_in[13];
  const float* g2   = (const float*)d_in[14];
  const float* be2  = (const float*)d_in[15];
  const float* g3   = (const float*)d_in[16];
  const float* be3  = (const float*)d_in[17];
  const float* wl1  = (const float*)d_in[18];
  const float* bl1  = (const float*)d_in[19];
  const float* wl2  = (const float*)d_in[20];
  const float* bl2  = (const float*)d_in[21];

  const int N = in_sizes[0] / 32;
  const int E = in_sizes[1] / 2;
  const int* src  = ei;
  const int* dstp = ei + E;
  float* outp = (float*)d_out;

  size_t off = 0;
  auto alloc = [&](size_t bytes) -> void* {
    void* p = (char*)d_ws + off;
    off += (bytes + 255) & ~(size_t)255;
    return p;
  };
  int*   rowptr = (int*)alloc(((size_t)N + 1) * 4);
  int*   cursor = (int*)alloc((size_t)N * 4);
  int*   csr    = (int*)alloc((size_t)E * 4);   // first N ints double as deg scratch
  int*   bsum   = (int*)alloc(((size_t)N / 2048 + 2) * 4);
  float* h1     = (float*)alloc((size_t)N * 16 * 4);
  float* h2     = (float*)alloc((size_t)N * 64 * 4);
  float* mean3  = (float*)alloc((size_t)N * 64 * 4);
  float* bnsum1 = (float*)alloc(2 * 16 * 4);
  float* bnsum2 = (float*)alloc(2 * 64 * 4);
  float* bnsum3 = (float*)alloc(2 * 512 * 4);
  float* bnab1  = (float*)alloc(2 * 16 * 4);
  float* bnab2  = (float*)alloc(2 * 64 * 4);
  float* bnab3  = (float*)alloc(2 * 512 * 4);
  unsigned int* pmax = (unsigned int*)alloc((size_t)NUM_GRAPHS * 512 * 4);
  unsigned int* pmin = (unsigned int*)alloc((size_t)NUM_GRAPHS * 512 * 4);
  (void)ws_size;

  const float invN = 1.0f / (float)N;
  const int nb1 = (N + 2047) / 2048;

  // ---------- CSR build (by dst) ----------
  int* deg = csr;
  hipMemsetAsync(deg, 0, (size_t)N * 4, stream);
  deg_kernel<<<(E + 255) / 256, 256, 0, stream>>>(dstp, deg, E);
  scan1_kernel<<<nb1, 256, 0, stream>>>(deg, rowptr, bsum, N);
  scan2_kernel<<<1, 64, 0, stream>>>(bsum, nb1);
  scan3_kernel<<<(N + 255) / 256, 256, 0, stream>>>(bsum, rowptr, cursor, N, E);
  fill_kernel<<<(E + 255) / 256, 256, 0, stream>>>(src, dstp, cursor, csr, E);

  pool_init_kernel<<<(NUM_GRAPHS * 512 + 255) / 256, 256, 0, stream>>>(
      pmax, pmin, NUM_GRAPHS * 512);

  // ---------- layer 1: 32 -> 16 ----------
  hipMemsetAsync(bnsum1, 0, 2 * 16 * 4, stream);
  linear_kernel<32, 16, 1, false, false, false><<<dim3((N + 63) / 64, 1), 256, 0, stream>>>(
      nullptr, rowptr, csr, x, w1_l, b1, w1_r, nullptr, h1, bnsum1, nullptr, nullptr, nullptr, N);
  bn_finalize<16><<<1, 16, 0, stream>>>(bnsum1, g1, be1, bnab1, invN);

  // ---------- layer 2: 16 -> 64 ----------
  hipMemsetAsync(bnsum2, 0, 2 * 64 * 4, stream);
  linear_kernel<16, 64, 4, true, false, false><<<dim3((N + 63) / 64, 1), 256, 0, stream>>>(
      nullptr, rowptr, csr, h1, w2_l, b2, w2_r, bnab1, h2, bnsum2, nullptr, nullptr, nullptr, N);
  bn_finalize<64><<<1, 64, 0, stream>>>(bnsum2, g2, be2, bnab2, invN);

  // ---------- layer 3: 64 -> 512, fused pre-BN min/max pool ----------
  hipMemsetAsync(bnsum3, 0, 2 * 512 * 4, stream);
  gather_mean_kernel<64, true><<<(N + 63) / 64, 256, 0, stream>>>(
      h2, rowptr, csr, bnab2, mean3, N);
  linear_kernel<64, 512, 8, true, true, true><<<dim3((N + 63) / 64, 4), 256, 0, stream>>>(
      mean3, nullptr, nullptr, h2, w3_l, b3, w3_r, bnab2, nullptr, bnsum3, batch, pmax, pmin, N);
  bn_finalize<512><<<1, 512, 0, stream>>>(bnsum3, g3, be3, bnab3, invN);

  // ---------- head ----------
  head_kernel<<<NUM_GRAPHS, 256, 0, stream>>>(pmax, pmin, bnab3, wl1, bl1, wl2, bl2, outp);
}

// Round 5
// 506.967 us; speedup vs baseline: 3.3770x; 1.3755x over previous
//
#include <hip/hip_runtime.h>
#include <hip/hip_bf16.h>
#include <cstdint>

#define NUM_GRAPHS 128
constexpr float EPSF = 1e-5f;

using short8 = __attribute__((ext_vector_type(8))) short;
using f32x4  = __attribute__((ext_vector_type(4))) float;

// order-preserving float<->uint key (works for negatives)
__device__ __forceinline__ unsigned int enc_key(float f) {
  unsigned int b = __float_as_uint(f);
  return (b & 0x80000000u) ? ~b : (b | 0x80000000u);
}
__device__ __forceinline__ float dec_key(unsigned int k) {
  return __uint_as_float((k & 0x80000000u) ? (k ^ 0x80000000u) : ~k);
}

// manual bf16 RNE conversion (finite values)
__device__ __forceinline__ unsigned short f2bf(float v) {
  unsigned int u = __float_as_uint(v);
  u += 0x7FFFu + ((u >> 16) & 1u);
  return (unsigned short)(u >> 16);
}
__device__ __forceinline__ float bf2f(unsigned short h) {
  return __uint_as_float(((unsigned int)h) << 16);
}

// ================= CSR build =================
__global__ __launch_bounds__(256) void deg_kernel(const int* __restrict__ dst,
                                                  int* __restrict__ deg, int E) {
  int e = blockIdx.x * 256 + threadIdx.x;
  if (e < E) atomicAdd(&deg[dst[e]], 1);
}

__global__ __launch_bounds__(256) void scan1_kernel(const int* __restrict__ deg,
                                                    int* __restrict__ excl,
                                                    int* __restrict__ bsum, int N) {
  __shared__ int ts[256];
  const int base = blockIdx.x * 2048;
  const int tid = threadIdx.x;
  int v[8];
  int tsum = 0;
  const int tb = base + tid * 8;
#pragma unroll
  for (int j = 0; j < 8; ++j) {
    int idx = tb + j;
    v[j] = (idx < N) ? deg[idx] : 0;
    tsum += v[j];
  }
  ts[tid] = tsum;
  __syncthreads();
  for (int off = 1; off < 256; off <<= 1) {
    int add = (tid >= off) ? ts[tid - off] : 0;
    __syncthreads();
    ts[tid] += add;
    __syncthreads();
  }
  int run = ts[tid] - tsum;
#pragma unroll
  for (int j = 0; j < 8; ++j) {
    int idx = tb + j;
    if (idx < N) excl[idx] = run;
    run += v[j];
  }
  if (tid == 255) bsum[blockIdx.x] = ts[255];
}

__global__ void scan2_kernel(int* __restrict__ bsum, int nb) {
  if (threadIdx.x == 0 && blockIdx.x == 0) {
    int run = 0;
    for (int i = 0; i < nb; ++i) { int t = bsum[i]; bsum[i] = run; run += t; }
  }
}

__global__ __launch_bounds__(256) void scan3_kernel(const int* __restrict__ bsum,
                                                    int* __restrict__ rowptr,
                                                    int* __restrict__ cursor,
                                                    int N, int E) {
  int i = blockIdx.x * 256 + threadIdx.x;
  if (i < N) {
    int v = rowptr[i] + bsum[i >> 11];
    rowptr[i] = v;
    cursor[i] = v;
  }
  if (i == 0) rowptr[N] = E;
}

__global__ __launch_bounds__(256) void fill_kernel(const int* __restrict__ src,
                                                   const int* __restrict__ dst,
                                                   int* __restrict__ cursor,
                                                   int* __restrict__ csr, int E) {
  int e = blockIdx.x * 256 + threadIdx.x;
  if (e < E) {
    int pos = atomicAdd(&cursor[dst[e]], 1);
    csr[pos] = src[e];
  }
}

// ================= pooled-key init =================
__global__ __launch_bounds__(256) void pool_init_kernel(unsigned int* __restrict__ pmax,
                                                        unsigned int* __restrict__ pmin, int n) {
  int i = blockIdx.x * 256 + threadIdx.x;
  if (i < n) { pmax[i] = 0x007FFFFFu; pmin[i] = 0xFF800000u; }
}

// ================= weight vector load (fp32 path, layers 1-2) =================
template <int RJ>
__device__ __forceinline__ void loadw(const float* __restrict__ p, float* w) {
  if constexpr (RJ == 1) {
    w[0] = p[0];
  } else if constexpr (RJ == 4) {
    const float4 v = *reinterpret_cast<const float4*>(p);
    w[0] = v.x; w[1] = v.y; w[2] = v.z; w[3] = v.w;
  } else {
    const float4 v0 = *reinterpret_cast<const float4*>(p);
    const float4 v1 = *reinterpret_cast<const float4*>(p + 4);
    w[0] = v0.x; w[1] = v0.y; w[2] = v0.z; w[3] = v0.w;
    w[4] = v1.x; w[5] = v1.y; w[6] = v1.z; w[7] = v1.w;
  }
}

// ================= fused node linear (fp32; layers 1-2) =================
template <int DIN, int DOUT, int RJ, bool BNIN>
__global__ __launch_bounds__(256) void linear_kernel(
    const int* __restrict__ rowptr, const int* __restrict__ csr,
    const float* __restrict__ xin, const float* __restrict__ wl,
    const float* __restrict__ bias, const float* __restrict__ wr,
    const float* __restrict__ ab_in, float* __restrict__ out,
    float* __restrict__ bnsum_out, int N) {
  constexpr int K2P = 2 * DIN + 1;
  __shared__ float As[64 * K2P];
  const int nb = blockIdx.x * 64;
  const int tid = threadIdx.x;

  {
    constexpr int NF4 = DIN / 16;
    const int nl = tid >> 2, t = tid & 3;
    const int n = nb + nl;
    float4 acc[NF4];
#pragma unroll
    for (int i = 0; i < NF4; ++i) acc[i] = make_float4(0.f, 0.f, 0.f, 0.f);
    float sc = 0.f;
    if (n < N) {
      float4 a4[NF4], b4[NF4];
      if (BNIN) {
#pragma unroll
        for (int i = 0; i < NF4; ++i) {
          a4[i] = *reinterpret_cast<const float4*>(&ab_in[(t + 4 * i) * 4]);
          b4[i] = *reinterpret_cast<const float4*>(&ab_in[DIN + (t + 4 * i) * 4]);
        }
      }
      const int r0 = rowptr[n], r1 = rowptr[n + 1];
      for (int p = r0; p < r1; ++p) {
        const float4* row = reinterpret_cast<const float4*>(xin + (size_t)csr[p] * DIN);
#pragma unroll
        for (int i = 0; i < NF4; ++i) {
          float4 v = row[t + 4 * i];
          if (BNIN) {
            v.x = fmaxf(fmaf(v.x, a4[i].x, b4[i].x), 0.f);
            v.y = fmaxf(fmaf(v.y, a4[i].y, b4[i].y), 0.f);
            v.z = fmaxf(fmaf(v.z, a4[i].z, b4[i].z), 0.f);
            v.w = fmaxf(fmaf(v.w, a4[i].w, b4[i].w), 0.f);
          }
          acc[i].x += v.x; acc[i].y += v.y; acc[i].z += v.z; acc[i].w += v.w;
        }
      }
      sc = 1.0f / fmaxf((float)(r1 - r0), 1.0f);
    }
#pragma unroll
    for (int i = 0; i < NF4; ++i) {
      int f = (t + 4 * i) * 4;
      As[nl * K2P + f + 0] = acc[i].x * sc;
      As[nl * K2P + f + 1] = acc[i].y * sc;
      As[nl * K2P + f + 2] = acc[i].z * sc;
      As[nl * K2P + f + 3] = acc[i].w * sc;
    }
  }

  {
    constexpr int R4 = DIN / 4;
    for (int idx4 = tid; idx4 < 64 * R4; idx4 += 256) {
      int nl = idx4 / R4, k4 = idx4 % R4;
      int n = nb + nl;
      float4 v = make_float4(0.f, 0.f, 0.f, 0.f);
      if (n < N) {
        v = reinterpret_cast<const float4*>(xin + (size_t)n * DIN)[k4];
        if (BNIN) {
          const float4 A = *reinterpret_cast<const float4*>(&ab_in[k4 * 4]);
          const float4 B = *reinterpret_cast<const float4*>(&ab_in[DIN + k4 * 4]);
          v.x = fmaxf(fmaf(v.x, A.x, B.x), 0.f);
          v.y = fmaxf(fmaf(v.y, A.y, B.y), 0.f);
          v.z = fmaxf(fmaf(v.z, A.z, B.z), 0.f);
          v.w = fmaxf(fmaf(v.w, A.w, B.w), 0.f);
        }
      }
      As[nl * K2P + DIN + k4 * 4 + 0] = v.x;
      As[nl * K2P + DIN + k4 * 4 + 1] = v.y;
      As[nl * K2P + DIN + k4 * 4 + 2] = v.z;
      As[nl * K2P + DIN + k4 * 4 + 3] = v.w;
    }
  }
  __syncthreads();

  const int ty = tid >> 4, tx = tid & 15;
  const int j0 = tx * RJ;
  float acc[4][RJ];
#pragma unroll
  for (int r = 0; r < 4; ++r)
#pragma unroll
    for (int c = 0; c < RJ; ++c) acc[r][c] = 0.f;

  const float* A0 = &As[(ty * 4 + 0) * K2P];
  const float* A1 = &As[(ty * 4 + 1) * K2P];
  const float* A2 = &As[(ty * 4 + 2) * K2P];
  const float* A3 = &As[(ty * 4 + 3) * K2P];

#pragma unroll 4
  for (int k = 0; k < DIN; ++k) {
    float w[RJ];
    loadw<RJ>(wl + (size_t)k * DOUT + j0, w);
    float a0 = A0[k], a1 = A1[k], a2 = A2[k], a3 = A3[k];
#pragma unroll
    for (int c = 0; c < RJ; ++c) {
      acc[0][c] = fmaf(a0, w[c], acc[0][c]);
      acc[1][c] = fmaf(a1, w[c], acc[1][c]);
      acc[2][c] = fmaf(a2, w[c], acc[2][c]);
      acc[3][c] = fmaf(a3, w[c], acc[3][c]);
    }
  }
#pragma unroll 4
  for (int k = 0; k < DIN; ++k) {
    float w[RJ];
    loadw<RJ>(wr + (size_t)k * DOUT + j0, w);
    float a0 = A0[DIN + k], a1 = A1[DIN + k], a2 = A2[DIN + k], a3 = A3[DIN + k];
#pragma unroll
    for (int c = 0; c < RJ; ++c) {
      acc[0][c] = fmaf(a0, w[c], acc[0][c]);
      acc[1][c] = fmaf(a1, w[c], acc[1][c]);
      acc[2][c] = fmaf(a2, w[c], acc[2][c]);
      acc[3][c] = fmaf(a3, w[c], acc[3][c]);
    }
  }

  float bv[RJ];
#pragma unroll
  for (int c = 0; c < RJ; ++c) bv[c] = bias[j0 + c];

  float s[RJ], q[RJ];
#pragma unroll
  for (int c = 0; c < RJ; ++c) { s[c] = 0.f; q[c] = 0.f; }
#pragma unroll
  for (int r = 0; r < 4; ++r) {
    int n = nb + ty * 4 + r;
    if (n < N) {
#pragma unroll
      for (int c = 0; c < RJ; ++c) {
        float v = acc[r][c] + bv[c];
        out[(size_t)n * DOUT + j0 + c] = v;
        s[c] += v;
        q[c] += v * v;
      }
    }
  }

  constexpr int F = 16 * RJ;
  __syncthreads();
  float* sL = As;
  float* qL = As + 16 * F;
#pragma unroll
  for (int c = 0; c < RJ; ++c) {
    sL[ty * F + tx * RJ + c] = s[c];
    qL[ty * F + tx * RJ + c] = q[c];
  }
  __syncthreads();
  for (int f = tid; f < F; f += 256) {
    float ss = 0.f, qq = 0.f;
#pragma unroll
    for (int t = 0; t < 16; ++t) { ss += sL[t * F + f]; qq += qL[t * F + f]; }
    atomicAdd(&bnsum_out[f], ss);
    atomicAdd(&bnsum_out[DOUT + f], qq);
  }
}

// ================= BN finalize =================
template <int D>
__global__ void bn_finalize(const float* __restrict__ sums, const float* __restrict__ g,
                            const float* __restrict__ be, float* __restrict__ ab, float invN) {
  int f = blockIdx.x * blockDim.x + threadIdx.x;
  if (f >= D) return;
  float m = sums[f] * invN;
  float var = sums[D + f] * invN - m * m;
  float a = g[f] * rsqrtf(var + EPSF);
  ab[f] = a;
  ab[D + f] = be[f] - m * a;
}

// ================= prep3: xb = bf16_hi/lo(relu(bn2(h2))) =================
__global__ __launch_bounds__(256) void prep3_kernel(const float* __restrict__ h2,
                                                    const float* __restrict__ ab,
                                                    unsigned short* __restrict__ xh,
                                                    unsigned short* __restrict__ xl,
                                                    int total) {
  int idx = (blockIdx.x * 256 + threadIdx.x) * 4;
  if (idx >= total) return;
  float4 v = *reinterpret_cast<const float4*>(h2 + idx);
  int f = idx & 63;
  const float4 A = *reinterpret_cast<const float4*>(&ab[f]);
  const float4 B = *reinterpret_cast<const float4*>(&ab[64 + f]);
  float r0 = fmaxf(fmaf(v.x, A.x, B.x), 0.f);
  float r1 = fmaxf(fmaf(v.y, A.y, B.y), 0.f);
  float r2 = fmaxf(fmaf(v.z, A.z, B.z), 0.f);
  float r3 = fmaxf(fmaf(v.w, A.w, B.w), 0.f);
  unsigned short h0 = f2bf(r0), h1 = f2bf(r1), h2s = f2bf(r2), h3 = f2bf(r3);
  unsigned short l0 = f2bf(r0 - bf2f(h0)), l1 = f2bf(r1 - bf2f(h1));
  unsigned short l2 = f2bf(r2 - bf2f(h2s)), l3 = f2bf(r3 - bf2f(h3));
  uint2 uh, ul;
  uh.x = (unsigned)h0 | ((unsigned)h1 << 16); uh.y = (unsigned)h2s | ((unsigned)h3 << 16);
  ul.x = (unsigned)l0 | ((unsigned)l1 << 16); ul.y = (unsigned)l2 | ((unsigned)l3 << 16);
  *reinterpret_cast<uint2*>(xh + idx) = uh;
  *reinterpret_cast<uint2*>(xl + idx) = ul;
}

// ================= convw3: Bt[c][k] hi/lo from wl/wr (k<64 -> wl) =================
__global__ __launch_bounds__(256) void convw3_kernel(const float* __restrict__ wl,
                                                     const float* __restrict__ wr,
                                                     unsigned short* __restrict__ bth,
                                                     unsigned short* __restrict__ btl) {
  int idx = blockIdx.x * 256 + threadIdx.x;
  if (idx >= 512 * 16) return;
  int c = idx >> 4, k8 = idx & 15;
  unsigned int uh[4], ul[4];
#pragma unroll
  for (int jj = 0; jj < 4; ++jj) {
    unsigned short hh[2], ll[2];
#pragma unroll
    for (int t = 0; t < 2; ++t) {
      int k = k8 * 8 + jj * 2 + t;
      float w = (k < 64) ? wl[(size_t)k * 512 + c] : wr[(size_t)(k - 64) * 512 + c];
      hh[t] = f2bf(w);
      ll[t] = f2bf(w - bf2f(hh[t]));
    }
    uh[jj] = (unsigned)hh[0] | ((unsigned)hh[1] << 16);
    ul[jj] = (unsigned)ll[0] | ((unsigned)ll[1] << 16);
  }
  *reinterpret_cast<uint4*>(bth + (size_t)c * 128 + k8 * 8) = make_uint4(uh[0], uh[1], uh[2], uh[3]);
  *reinterpret_cast<uint4*>(btl + (size_t)c * 128 + k8 * 8) = make_uint4(ul[0], ul[1], ul[2], ul[3]);
}

// ================= gather-mean from bf16-hi, emits hi/lo =================
__global__ __launch_bounds__(256) void gather_mean_bf16(
    const unsigned short* __restrict__ xh, const int* __restrict__ rowptr,
    const int* __restrict__ csr, unsigned short* __restrict__ mh,
    unsigned short* __restrict__ ml, int N) {
  const int tid = threadIdx.x;
  const int nl = tid >> 2, t = tid & 3;
  const int n = blockIdx.x * 64 + nl;
  if (n >= N) return;
  float acc[16];
#pragma unroll
  for (int i = 0; i < 16; ++i) acc[i] = 0.f;
  const int r0 = rowptr[n], r1 = rowptr[n + 1];
  for (int p = r0; p < r1; ++p) {
    const unsigned short* row = xh + (size_t)csr[p] * 64 + t * 16;
    uint4 u0 = *reinterpret_cast<const uint4*>(row);
    uint4 u1 = *reinterpret_cast<const uint4*>(row + 8);
    unsigned int uu[8] = {u0.x, u0.y, u0.z, u0.w, u1.x, u1.y, u1.z, u1.w};
#pragma unroll
    for (int j = 0; j < 8; ++j) {
      acc[2 * j]     += bf2f((unsigned short)(uu[j] & 0xFFFFu));
      acc[2 * j + 1] += bf2f((unsigned short)(uu[j] >> 16));
    }
  }
  const float sc = 1.0f / fmaxf((float)(r1 - r0), 1.0f);
  unsigned int oh[8], ol[8];
#pragma unroll
  for (int j = 0; j < 8; ++j) {
    unsigned short hh[2], ll[2];
#pragma unroll
    for (int tt = 0; tt < 2; ++tt) {
      float m = acc[2 * j + tt] * sc;
      hh[tt] = f2bf(m);
      ll[tt] = f2bf(m - bf2f(hh[tt]));
    }
    oh[j] = (unsigned)hh[0] | ((unsigned)hh[1] << 16);
    ol[j] = (unsigned)ll[0] | ((unsigned)ll[1] << 16);
  }
  unsigned short* mrow = mh + (size_t)n * 64 + t * 16;
  unsigned short* lrow = ml + (size_t)n * 64 + t * 16;
  *reinterpret_cast<uint4*>(mrow)     = make_uint4(oh[0], oh[1], oh[2], oh[3]);
  *reinterpret_cast<uint4*>(mrow + 8) = make_uint4(oh[4], oh[5], oh[6], oh[7]);
  *reinterpret_cast<uint4*>(lrow)     = make_uint4(ol[0], ol[1], ol[2], ol[3]);
  *reinterpret_cast<uint4*>(lrow + 8) = make_uint4(ol[4], ol[5], ol[6], ol[7]);
}

// ================= layer-3 MFMA GEMM + fused BN stats + pre-BN min/max pool ===========
// A = [mean | x] (N x 128, bf16 hi+lo), Bt = weights transposed (512 x 128, bf16 hi+lo)
// block: 256 thr = 4 waves; tile 64 rows x 256 cols (wave w -> cols w*64..w*64+63)
__global__ __launch_bounds__(256) void mfma3_kernel(
    const unsigned short* __restrict__ mh, const unsigned short* __restrict__ ml,
    const unsigned short* __restrict__ xh, const unsigned short* __restrict__ xl,
    const unsigned short* __restrict__ bth, const unsigned short* __restrict__ btl,
    const float* __restrict__ bias, const int* __restrict__ batchp,
    float* __restrict__ bnsum, unsigned int* __restrict__ pmax,
    unsigned int* __restrict__ pmin, int N) {
  constexpr int LR = 136;  // ushorts per LDS row (128 + 8 pad -> 2-way bank alias only)
  __shared__ unsigned short Ah[64 * LR];
  __shared__ unsigned short Al[64 * LR];
  __shared__ int gb[64];
  const int tid = threadIdx.x;
  const int nb = blockIdx.x * 64;
  const int colbase = blockIdx.y * 256;

  {  // stage A tile: thread -> (row, 64B quarter)
    const int row = tid >> 2, q = tid & 3;
    const int n = nb + row;
    uint4 vh[4], vl[4];
    if (n < N) {
      const unsigned short* ph = (q < 2) ? (mh + (size_t)n * 64 + q * 32)
                                         : (xh + (size_t)n * 64 + (q - 2) * 32);
      const unsigned short* pl = (q < 2) ? (ml + (size_t)n * 64 + q * 32)
                                         : (xl + (size_t)n * 64 + (q - 2) * 32);
#pragma unroll
      for (int j = 0; j < 4; ++j) {
        vh[j] = reinterpret_cast<const uint4*>(ph)[j];
        vl[j] = reinterpret_cast<const uint4*>(pl)[j];
      }
    } else {
      uint4 z = make_uint4(0, 0, 0, 0);
#pragma unroll
      for (int j = 0; j < 4; ++j) { vh[j] = z; vl[j] = z; }
    }
    unsigned short* dh = &Ah[row * LR + q * 32];
    unsigned short* dl = &Al[row * LR + q * 32];
#pragma unroll
    for (int j = 0; j < 4; ++j) {
      *reinterpret_cast<uint4*>(dh + j * 8) = vh[j];
      *reinterpret_cast<uint4*>(dl + j * 8) = vl[j];
    }
  }
  if (tid < 64) gb[tid] = (nb + tid < N) ? batchp[nb + tid] : 0x7FFFFFFF;
  __syncthreads();

  const int wid = tid >> 6, lane = tid & 63;
  const int l16 = lane & 15, lg = lane >> 4;
  const int wcol = colbase + wid * 64;

  f32x4 acc[4][4];
#pragma unroll
  for (int rb = 0; rb < 4; ++rb)
#pragma unroll
    for (int cb = 0; cb < 4; ++cb) acc[rb][cb] = (f32x4){0.f, 0.f, 0.f, 0.f};

#pragma unroll
  for (int ks = 0; ks < 4; ++ks) {
    const int koff = ks * 32 + lg * 8;
    short8 ah[4], al[4], bh[4], bl[4];
#pragma unroll
    for (int rb = 0; rb < 4; ++rb) {
      ah[rb] = *reinterpret_cast<const short8*>(&Ah[(rb * 16 + l16) * LR + koff]);
      al[rb] = *reinterpret_cast<const short8*>(&Al[(rb * 16 + l16) * LR + koff]);
    }
#pragma unroll
    for (int cb = 0; cb < 4; ++cb) {
      const size_t boff = (size_t)(wcol + cb * 16 + l16) * 128 + koff;
      bh[cb] = *reinterpret_cast<const short8*>(bth + boff);
      bl[cb] = *reinterpret_cast<const short8*>(btl + boff);
    }
#pragma unroll
    for (int rb = 0; rb < 4; ++rb)
#pragma unroll
      for (int cb = 0; cb < 4; ++cb) {
        acc[rb][cb] = __builtin_amdgcn_mfma_f32_16x16x32_bf16(al[rb], bh[cb], acc[rb][cb], 0, 0, 0);
        acc[rb][cb] = __builtin_amdgcn_mfma_f32_16x16x32_bf16(ah[rb], bl[cb], acc[rb][cb], 0, 0, 0);
        acc[rb][cb] = __builtin_amdgcn_mfma_f32_16x16x32_bf16(ah[rb], bh[cb], acc[rb][cb], 0, 0, 0);
      }
  }

  // epilogue: bias, BN stats, pre-BN min/max graph pool
  const bool uni = (gb[0] == gb[63]);
  const int g0 = gb[0];
#pragma unroll
  for (int cb = 0; cb < 4; ++cb) {
    const int col = wcol + cb * 16 + l16;
    const float bv = bias[col];
    float s = 0.f, q = 0.f, mx = -INFINITY, mn = INFINITY;
#pragma unroll
    for (int rb = 0; rb < 4; ++rb)
#pragma unroll
      for (int r = 0; r < 4; ++r) {
        const int row = rb * 16 + lg * 4 + r;
        float v = acc[rb][cb][r] + bv;
        acc[rb][cb][r] = v;
        if (nb + row < N) {
          s += v; q += v * v;
          mx = fmaxf(mx, v); mn = fminf(mn, v);
        }
      }
    s += __shfl_xor(s, 16); s += __shfl_xor(s, 32);
    q += __shfl_xor(q, 16); q += __shfl_xor(q, 32);
    if (lane < 16) {
      atomicAdd(&bnsum[col], s);
      atomicAdd(&bnsum[512 + col], q);
    }
    if (uni) {
      mx = fmaxf(mx, __shfl_xor(mx, 16)); mx = fmaxf(mx, __shfl_xor(mx, 32));
      mn = fminf(mn, __shfl_xor(mn, 16)); mn = fminf(mn, __shfl_xor(mn, 32));
      if (lane < 16) {
        atomicMax(&pmax[(size_t)g0 * 512 + col], enc_key(mx));
        atomicMin(&pmin[(size_t)g0 * 512 + col], enc_key(mn));
      }
    } else {
      int curg = -1;
      float rmx = -INFINITY, rmn = INFINITY;
#pragma unroll
      for (int rb = 0; rb < 4; ++rb)
#pragma unroll
        for (int r = 0; r < 4; ++r) {
          const int row = rb * 16 + lg * 4 + r;
          const int g = gb[row];
          if (g != curg) {
            if (curg >= 0 && curg != 0x7FFFFFFF) {
              atomicMax(&pmax[(size_t)curg * 512 + col], enc_key(rmx));
              atomicMin(&pmin[(size_t)curg * 512 + col], enc_key(rmn));
            }
            curg = g; rmx = -INFINITY; rmn = INFINITY;
          }
          if (g != 0x7FFFFFFF) {
            const float v = acc[rb][cb][r];
            rmx = fmaxf(rmx, v); rmn = fminf(rmn, v);
          }
        }
      if (curg >= 0 && curg != 0x7FFFFFFF) {
        atomicMax(&pmax[(size_t)curg * 512 + col], enc_key(rmx));
        atomicMin(&pmin[(size_t)curg * 512 + col], enc_key(rmn));
      }
    }
  }
}

// ================= MLP head (decodes pooled keys, applies BN3+ReLU) =================
__global__ __launch_bounds__(256) void head_kernel(const unsigned int* __restrict__ pmax,
                                                   const unsigned int* __restrict__ pmin,
                                                   const float* __restrict__ ab,
                                                   const float* __restrict__ w1,
                                                   const float* __restrict__ b1,
                                                   const float* __restrict__ w2,
                                                   const float* __restrict__ b2,
                                                   float* __restrict__ out) {
  __shared__ float pr[512];
  __shared__ float hid[256];
  int g = blockIdx.x;
  int t = threadIdx.x;
  for (int i = t; i < 512; i += 256) {
    float a = ab[i], b = ab[512 + i];
    float v = (a >= 0.f) ? dec_key(pmax[(size_t)g * 512 + i])
                         : dec_key(pmin[(size_t)g * 512 + i]);
    pr[i] = fmaxf(fmaf(v, a, b), 0.f);
  }
  __syncthreads();
  float acc = b1[t];
  for (int i = 0; i < 512; ++i) acc = fmaf(pr[i], w1[(size_t)i * 256 + t], acc);
  hid[t] = fmaxf(acc, 0.f);
  __syncthreads();
  if (t < 10) {
    float o = b2[t];
    for (int j = 0; j < 256; ++j) o = fmaf(hid[j], w2[(size_t)j * 10 + t], o);
    out[(size_t)g * 10 + t] = o;
  }
}

extern "C" void kernel_launch(void* const* d_in, const int* in_sizes, int n_in,
                              void* d_out, int out_size, void* d_ws, size_t ws_size,
                              hipStream_t stream) {
  const float* x    = (const float*)d_in[0];
  const int*   ei   = (const int*)d_in[1];
  const int*   batch= (const int*)d_in[2];
  const float* w1_l = (const float*)d_in[3];
  const float* b1   = (const float*)d_in[4];
  const float* w1_r = (const float*)d_in[5];
  const float* w2_l = (const float*)d_in[6];
  const float* b2   = (const float*)d_in[7];
  const float* w2_r = (const float*)d_in[8];
  const float* w3_l = (const float*)d_in[9];
  const float* b3   = (const float*)d_in[10];
  const float* w3_r = (const float*)d_in[11];
  const float* g1   = (const float*)d_in[12];
  const float* be1  = (const float*)d_in[13];
  const float* g2   = (const float*)d_in[14];
  const float* be2  = (const float*)d_in[15];
  const float* g3   = (const float*)d_in[16];
  const float* be3  = (const float*)d_in[17];
  const float* wl1  = (const float*)d_in[18];
  const float* bl1  = (const float*)d_in[19];
  const float* wl2  = (const float*)d_in[20];
  const float* bl2  = (const float*)d_in[21];

  const int N = in_sizes[0] / 32;
  const int E = in_sizes[1] / 2;
  const int* src  = ei;
  const int* dstp = ei + E;
  float* outp = (float*)d_out;

  size_t off = 0;
  auto alloc = [&](size_t bytes) -> void* {
    void* p = (char*)d_ws + off;
    off += (bytes + 255) & ~(size_t)255;
    return p;
  };
  int*   rowptr = (int*)alloc(((size_t)N + 1) * 4);
  int*   cursor = (int*)alloc((size_t)N * 4);
  int*   csr    = (int*)alloc((size_t)E * 4);   // first N ints double as deg scratch
  int*   bsum   = (int*)alloc(((size_t)N / 2048 + 2) * 4);
  float* h1     = (float*)alloc((size_t)N * 16 * 4);
  float* h2     = (float*)alloc((size_t)N * 64 * 4);
  unsigned short* xh = (unsigned short*)alloc((size_t)N * 64 * 2);
  unsigned short* xl = (unsigned short*)alloc((size_t)N * 64 * 2);
  unsigned short* mh = (unsigned short*)alloc((size_t)N * 64 * 2);
  unsigned short* ml = (unsigned short*)alloc((size_t)N * 64 * 2);
  unsigned short* bth = (unsigned short*)alloc(512 * 128 * 2);
  unsigned short* btl = (unsigned short*)alloc(512 * 128 * 2);
  float* bnsum1 = (float*)alloc(2 * 16 * 4);
  float* bnsum2 = (float*)alloc(2 * 64 * 4);
  float* bnsum3 = (float*)alloc(2 * 512 * 4);
  float* bnab1  = (float*)alloc(2 * 16 * 4);
  float* bnab2  = (float*)alloc(2 * 64 * 4);
  float* bnab3  = (float*)alloc(2 * 512 * 4);
  unsigned int* pmax = (unsigned int*)alloc((size_t)NUM_GRAPHS * 512 * 4);
  unsigned int* pmin = (unsigned int*)alloc((size_t)NUM_GRAPHS * 512 * 4);
  (void)ws_size;

  const float invN = 1.0f / (float)N;
  const int nb1 = (N + 2047) / 2048;

  // ---------- CSR build (by dst) ----------
  int* deg = csr;
  hipMemsetAsync(deg, 0, (size_t)N * 4, stream);
  deg_kernel<<<(E + 255) / 256, 256, 0, stream>>>(dstp, deg, E);
  scan1_kernel<<<nb1, 256, 0, stream>>>(deg, rowptr, bsum, N);
  scan2_kernel<<<1, 64, 0, stream>>>(bsum, nb1);
  scan3_kernel<<<(N + 255) / 256, 256, 0, stream>>>(bsum, rowptr, cursor, N, E);
  fill_kernel<<<(E + 255) / 256, 256, 0, stream>>>(src, dstp, cursor, csr, E);

  pool_init_kernel<<<(NUM_GRAPHS * 512 + 255) / 256, 256, 0, stream>>>(
      pmax, pmin, NUM_GRAPHS * 512);
  convw3_kernel<<<(512 * 16 + 255) / 256, 256, 0, stream>>>(w3_l, w3_r, bth, btl);

  // ---------- layer 1: 32 -> 16 ----------
  hipMemsetAsync(bnsum1, 0, 2 * 16 * 4, stream);
  linear_kernel<32, 16, 1, false><<<(N + 63) / 64, 256, 0, stream>>>(
      rowptr, csr, x, w1_l, b1, w1_r, nullptr, h1, bnsum1, N);
  bn_finalize<16><<<1, 16, 0, stream>>>(bnsum1, g1, be1, bnab1, invN);

  // ---------- layer 2: 16 -> 64 ----------
  hipMemsetAsync(bnsum2, 0, 2 * 64 * 4, stream);
  linear_kernel<16, 64, 4, true><<<(N + 63) / 64, 256, 0, stream>>>(
      rowptr, csr, h1, w2_l, b2, w2_r, bnab1, h2, bnsum2, N);
  bn_finalize<64><<<1, 64, 0, stream>>>(bnsum2, g2, be2, bnab2, invN);

  // ---------- layer 3: 64 -> 512 via MFMA (hi/lo bf16 split) ----------
  prep3_kernel<<<((N * 64 / 4) + 255) / 256, 256, 0, stream>>>(h2, bnab2, xh, xl, N * 64);
  gather_mean_bf16<<<(N + 63) / 64, 256, 0, stream>>>(xh, rowptr, csr, mh, ml, N);
  hipMemsetAsync(bnsum3, 0, 2 * 512 * 4, stream);
  mfma3_kernel<<<dim3((N + 63) / 64, 2), 256, 0, stream>>>(
      mh, ml, xh, xl, bth, btl, b3, batch, bnsum3, pmax, pmin, N);
  bn_finalize<512><<<1, 512, 0, stream>>>(bnsum3, g3, be3, bnab3, invN);

  // ---------- head ----------
  head_kernel<<<NUM_GRAPHS, 256, 0, stream>>>(pmax, pmin, bnab3, wl1, bl1, wl2, bl2, outp);
}